// Round 1
// baseline (508.780 us; speedup 1.0000x reference)
//
#include <hip/hip_runtime.h>
#include <hip/hip_bf16.h>
#include <math.h>

typedef __attribute__((ext_vector_type(8))) short bf16x8;
typedef __attribute__((ext_vector_type(4))) float f32x4;
typedef __attribute__((ext_vector_type(4))) short short4v;
typedef __attribute__((ext_vector_type(4))) int int4v;

__device__ __forceinline__ short f2bf(float f) {
  union { float f; unsigned u; } v; v.f = f;
  unsigned r = v.u + 0x7fffu + ((v.u >> 16) & 1u);
  return (short)(r >> 16);
}

// ---------------- conversion kernels ----------------

__global__ void convert_x_kernel(const float* __restrict__ x, short* __restrict__ xb, int n) {
  int i = (blockIdx.x * blockDim.x + threadIdx.x) * 4;
  int stride = gridDim.x * blockDim.x * 4;
  for (; i < n; i += stride) {
    float4 v = *(const float4*)(x + i);
    short4v o;
    o.x = f2bf(v.x); o.y = f2bf(v.y); o.z = f2bf(v.z); o.w = f2bf(v.w);
    *(short4v*)(xb + i) = o;
  }
}

// W [2048][6144] f32 -> Wt [6144][2048] bf16
__global__ void transpose_w_kernel(const float* __restrict__ W, short* __restrict__ Wt) {
  __shared__ short tile[32][33];
  int n0 = blockIdx.x * 32, k0 = blockIdx.y * 32;
  int tx = threadIdx.x, ty = threadIdx.y; // (32, 8)
#pragma unroll
  for (int u = 0; u < 4; ++u) {
    int k = k0 + ty + u * 8;
    tile[ty + u * 8][tx] = f2bf(W[(size_t)k * 6144 + n0 + tx]);
  }
  __syncthreads();
#pragma unroll
  for (int u = 0; u < 4; ++u) {
    int n = n0 + ty + u * 8;
    Wt[(size_t)n * 2048 + k0 + tx] = tile[tx][ty + u * 8];
  }
}

// Normalize mask to u8 0/1, detecting storage layout (bool-bytes / int32 / f32).
__global__ void mask_norm_kernel(const unsigned* __restrict__ m, unsigned char* __restrict__ out, int n) {
  __shared__ int flagA, flagB;
  if (threadIdx.x == 0) { flagA = 0; flagB = 0; }
  __syncthreads();
  int a = 0, b = 0;
  // scan only the first n bytes' worth of words (valid under every interpretation)
  for (int i = threadIdx.x; i < n / 4; i += blockDim.x) {
    unsigned wv = m[i];
    if (wv > 1u) a = 1;
    if (wv != 0u && wv != 0x3f800000u) b = 1;
  }
  if (a) atomicOr(&flagA, 1);
  if (b) atomicOr(&flagB, 1);
  __syncthreads();
  int A = flagA, B = flagB;
  for (int i = threadIdx.x; i < n; i += blockDim.x) {
    unsigned char r;
    if (!A) r = (m[i] != 0u) ? 1 : 0;                                  // int32 0/1
    else if (!B) r = (((const float*)m)[i] != 0.f) ? 1 : 0;            // float32
    else r = (((const unsigned char*)m)[i] != 0) ? 1 : 0;              // bool bytes
    out[i] = r;
  }
}

// ---------------- QKV GEMM (m97 structure) ----------------
// A: x bf16 [4096][2048]; Bt: Wt bf16 [6144][2048]; out: Q,K [B,H,S,128] bf16, Vt [B,H,128,S] bf16

__global__ __launch_bounds__(256, 2) void qkv_gemm_kernel(
    const short* __restrict__ A, const short* __restrict__ Bt, const float* __restrict__ bias,
    short* __restrict__ qws, short* __restrict__ kws, short* __restrict__ vtws) {
  __shared__ short As[128 * 32];
  __shared__ short Bs[128 * 32];
  __shared__ short Vs[64 * 136];

  const int K = 2048;
  int lid = blockIdx.x;                     // 1536 blocks, 1536 % 8 == 0
  int swz = (lid & 7) * 192 + (lid >> 3);   // XCD-contiguous chunks
  int tm = swz / 48, tn = swz % 48;
  int m0 = tm * 128, n0 = tn * 128;
  int t = threadIdx.x, lane = t & 63, w = t >> 6;
  int wr = w >> 1, wc = w & 1;
  int g = lane >> 4, c = lane & 15;

  f32x4 acc[4][4] = {};

  for (int k0 = 0; k0 < K; k0 += 32) {
#pragma unroll
    for (int rep = 0; rep < 2; ++rep) {
      int chunk = rep * 256 + t;
      int row = chunk >> 2, cc = chunk & 3;
      const short* ga = A + (size_t)(m0 + row) * K + (k0 + cc * 8);
      __builtin_amdgcn_global_load_lds((const __attribute__((address_space(1))) void*)ga,
          (__attribute__((address_space(3))) void*)(As + chunk * 8), 16, 0, 0);
      const short* gb = Bt + (size_t)(n0 + row) * K + (k0 + cc * 8);
      __builtin_amdgcn_global_load_lds((const __attribute__((address_space(1))) void*)gb,
          (__attribute__((address_space(3))) void*)(Bs + chunk * 8), 16, 0, 0);
    }
    __syncthreads();
    bf16x8 ar[4], br[4];
#pragma unroll
    for (int i = 0; i < 4; ++i) ar[i] = *(const bf16x8*)(As + (wr * 64 + i * 16 + c) * 32 + g * 8);
#pragma unroll
    for (int j = 0; j < 4; ++j) br[j] = *(const bf16x8*)(Bs + (wc * 64 + j * 16 + c) * 32 + g * 8);
#pragma unroll
    for (int i = 0; i < 4; ++i)
#pragma unroll
      for (int j = 0; j < 4; ++j)
        acc[i][j] = __builtin_amdgcn_mfma_f32_16x16x32_bf16(ar[i], br[j], acc[i][j], 0, 0, 0);
    __syncthreads();
  }

  // epilogue: tile-uniform section/head (since 128 | 2048)
  int sec = n0 >> 11;
  int h = (n0 >> 7) & 15;
  int b = m0 >> 11;
  int s0 = m0 & 2047;
  size_t bh = (size_t)(b * 16 + h);

  if (sec < 2) {
    short* dst = (sec == 0 ? qws : kws) + bh * (size_t)(2048 * 128);
#pragma unroll
    for (int i = 0; i < 4; ++i)
#pragma unroll
      for (int j = 0; j < 4; ++j) {
        int dcol = wc * 64 + j * 16 + c;
        float bv = bias[n0 + dcol];
#pragma unroll
        for (int r = 0; r < 4; ++r) {
          int srow = s0 + wr * 64 + i * 16 + g * 4 + r;
          dst[(size_t)srow * 128 + dcol] = f2bf(acc[i][j][r] + bv);
        }
      }
  } else {
    // V: transpose through LDS so Vt stores are coalesced along s
    short* dst = vtws + bh * (size_t)(128 * 2048);
#pragma unroll
    for (int hs = 0; hs < 2; ++hs) {
      if (wr == hs) {
#pragma unroll
        for (int i = 0; i < 4; ++i)
#pragma unroll
          for (int j = 0; j < 4; ++j) {
            int dcol = wc * 64 + j * 16 + c;
            float bv = bias[n0 + dcol];
#pragma unroll
            for (int r = 0; r < 4; ++r)
              Vs[(i * 16 + g * 4 + r) * 136 + dcol] = f2bf(acc[i][j][r] + bv);
          }
      }
      __syncthreads();
      {
        int d = t >> 1, sc = (t & 1) * 32;
        size_t off = (size_t)d * 2048 + s0 + hs * 64 + sc;
#pragma unroll
        for (int q = 0; q < 4; ++q) {
          int4v pk;
#pragma unroll
          for (int e = 0; e < 4; ++e) {
            int u = q * 8 + e * 2;
            unsigned lo = (unsigned short)Vs[(sc + u) * 136 + d];
            unsigned hi = (unsigned short)Vs[(sc + u + 1) * 136 + d];
            pk[e] = (int)(lo | (hi << 16));
          }
          ((int4v*)(dst + off))[q] = pk;
        }
      }
      __syncthreads();
    }
  }
}

// ---------------- flash attention ----------------
// Q,K: [B,H,S,128] bf16; Vt: [B,H,128,S] bf16; out: [B,S,H*128] f32

__global__ __launch_bounds__(256, 2) void attn_kernel(
    const short* __restrict__ qws, const short* __restrict__ kws, const short* __restrict__ vtws,
    const unsigned char* __restrict__ maskb, float* __restrict__ out) {
  __shared__ short P[4][32 * 40];  // per-wave private P tile, stride 40 (80B, 16B-aligned rows)
  const int S = 2048, HD = 128;
  int lid = blockIdx.x;                   // 512 blocks, 512 % 8 == 0
  int swz = (lid & 7) * 64 + (lid >> 3);  // group 4 heads per XCD (KV L2 locality)
  int bh = swz >> 4, qblk = swz & 15;
  int b = bh >> 4, h = bh & 15;
  int t = threadIdx.x, lane = t & 63, w = t >> 6, g = lane >> 4, c = lane & 15;
  int q0 = qblk * 128 + w * 32;
  const short* Q = qws + (size_t)bh * S * HD;
  const short* Kp = kws + (size_t)bh * S * HD;
  const short* Vt = vtws + (size_t)bh * HD * S;
  const unsigned char* mk = maskb + b * S;
  const float scale = 0.08838834764831845f;  // 128^-0.5
  const float NEG = -3.4028235e38f;

  bf16x8 qf[2][4];
#pragma unroll
  for (int rb = 0; rb < 2; ++rb)
#pragma unroll
    for (int kc = 0; kc < 4; ++kc)
      qf[rb][kc] = *(const bf16x8*)(Q + (size_t)(q0 + rb * 16 + c) * HD + kc * 32 + g * 8);

  f32x4 acc[2][8] = {};
  float m_[2][4], l_[2][4];
#pragma unroll
  for (int rb = 0; rb < 2; ++rb)
#pragma unroll
    for (int i = 0; i < 4; ++i) { m_[rb][i] = -INFINITY; l_[rb][i] = 0.f; }

  short* pl = &P[w][0];

  for (int kv0 = 0; kv0 < S; kv0 += 32) {
    bf16x8 kf[2][4];
#pragma unroll
    for (int nb = 0; nb < 2; ++nb)
#pragma unroll
      for (int kc = 0; kc < 4; ++kc)
        kf[nb][kc] = *(const bf16x8*)(Kp + (size_t)(kv0 + nb * 16 + c) * HD + kc * 32 + g * 8);

    f32x4 sv[2][2] = {};
#pragma unroll
    for (int rb = 0; rb < 2; ++rb)
#pragma unroll
      for (int nb = 0; nb < 2; ++nb)
#pragma unroll
        for (int kc = 0; kc < 4; ++kc)
          sv[rb][nb] = __builtin_amdgcn_mfma_f32_16x16x32_bf16(qf[rb][kc], kf[nb][kc], sv[rb][nb], 0, 0, 0);

    bool keep[2];
#pragma unroll
    for (int nb = 0; nb < 2; ++nb) keep[nb] = (mk[kv0 + nb * 16 + c] != 0);

    float p[2][2][4];
#pragma unroll
    for (int rb = 0; rb < 2; ++rb)
#pragma unroll
      for (int nb = 0; nb < 2; ++nb)
#pragma unroll
        for (int i = 0; i < 4; ++i)
          p[rb][nb][i] = keep[nb] ? sv[rb][nb][i] * scale : NEG;

#pragma unroll
    for (int rb = 0; rb < 2; ++rb) {
      float rmax[4], alpha[4], rs[4];
#pragma unroll
      for (int i = 0; i < 4; ++i) rmax[i] = fmaxf(p[rb][0][i], p[rb][1][i]);
#pragma unroll
      for (int d = 1; d < 16; d <<= 1)
#pragma unroll
        for (int i = 0; i < 4; ++i) rmax[i] = fmaxf(rmax[i], __shfl_xor(rmax[i], d));
#pragma unroll
      for (int i = 0; i < 4; ++i) {
        float mn = fmaxf(m_[rb][i], rmax[i]);
        alpha[i] = __expf(m_[rb][i] - mn);
        m_[rb][i] = mn;
        float e0 = __expf(p[rb][0][i] - mn);
        float e1 = __expf(p[rb][1][i] - mn);
        p[rb][0][i] = e0; p[rb][1][i] = e1;
        rs[i] = e0 + e1;
      }
#pragma unroll
      for (int d = 1; d < 16; d <<= 1)
#pragma unroll
        for (int i = 0; i < 4; ++i) rs[i] += __shfl_xor(rs[i], d);
#pragma unroll
      for (int i = 0; i < 4; ++i) l_[rb][i] = l_[rb][i] * alpha[i] + rs[i];
#pragma unroll
      for (int db = 0; db < 8; ++db)
#pragma unroll
        for (int i = 0; i < 4; ++i) acc[rb][db][i] *= alpha[i];
#pragma unroll
      for (int nb = 0; nb < 2; ++nb)
#pragma unroll
        for (int i = 0; i < 4; ++i)
          pl[(rb * 16 + g * 4 + i) * 40 + nb * 16 + c] = f2bf(p[rb][nb][i]);
    }

    // same-wave LDS in-order: no barrier needed (private per-wave P)
    bf16x8 pf[2];
#pragma unroll
    for (int rb = 0; rb < 2; ++rb)
      pf[rb] = *(const bf16x8*)(pl + (rb * 16 + c) * 40 + g * 8);

#pragma unroll
    for (int db = 0; db < 8; ++db) {
      bf16x8 vf = *(const bf16x8*)(Vt + (size_t)(db * 16 + c) * S + kv0 + g * 8);
#pragma unroll
      for (int rb = 0; rb < 2; ++rb)
        acc[rb][db] = __builtin_amdgcn_mfma_f32_16x16x32_bf16(pf[rb], vf, acc[rb][db], 0, 0, 0);
    }
  }

#pragma unroll
  for (int rb = 0; rb < 2; ++rb) {
    float inv[4];
#pragma unroll
    for (int i = 0; i < 4; ++i) inv[i] = 1.f / l_[rb][i];
#pragma unroll
    for (int db = 0; db < 8; ++db)
#pragma unroll
      for (int i = 0; i < 4; ++i) {
        int srow = q0 + rb * 16 + g * 4 + i;
        out[((size_t)(b * 2048 + srow)) * 2048 + h * 128 + db * 16 + c] = acc[rb][db][i] * inv[i];
      }
  }
}

// ---------------- launch ----------------

extern "C" void kernel_launch(void* const* d_in, const int* in_sizes, int n_in,
                              void* d_out, int out_size, void* d_ws, size_t ws_size,
                              hipStream_t stream) {
  const float* x = (const float*)d_in[0];
  const float* W = (const float*)d_in[1];
  const float* bias = (const float*)d_in[2];
  const void* mask = d_in[3];
  float* out = (float*)d_out;

  char* ws = (char*)d_ws;
  // layout (bytes): xb 16777216 | wt 25165824 | q 16777216 | k 16777216 | vt 16777216 | mask 4096
  short* xb = (short*)(ws);
  short* wt = (short*)(ws + 16777216);
  short* qws = (short*)(ws + 41943040);
  short* kws = (short*)(ws + 58720256);
  short* vtws = (short*)(ws + 75497472);
  unsigned char* maskb = (unsigned char*)(ws + 92274688);

  convert_x_kernel<<<dim3(2048), dim3(256), 0, stream>>>(x, xb, 2 * 2048 * 2048);
  transpose_w_kernel<<<dim3(192, 64), dim3(32, 8), 0, stream>>>(W, wt);
  mask_norm_kernel<<<dim3(1), dim3(256), 0, stream>>>((const unsigned*)mask, maskb, 2 * 2048);
  qkv_gemm_kernel<<<dim3(1536), dim3(256), 0, stream>>>(xb, wt, bias, qws, kws, vtws);
  attn_kernel<<<dim3(512), dim3(256), 0, stream>>>(qws, kws, vtws, maskb, out);
}